// Round 6
// baseline (311.622 us; speedup 1.0000x reference)
//
#include <hip/hip_runtime.h>
#include <math.h>

#define D 1024
#define NH 16
#define DK 64
#define S_LEN 2048
// 0.125 (1/sqrt(Dk)) * log2(e): softmax computed in base-2 domain, no max-subtraction
#define QSCALE 0.18033688011112f

using short8 = __attribute__((ext_vector_type(8))) short;   // 8 x bf16 (4 VGPR)
using f32x4  = __attribute__((ext_vector_type(4))) float;   // MFMA accumulator

#define MFMA16(a, b, c) __builtin_amdgcn_mfma_f32_16x16x32_bf16((a), (b), (c), 0, 0, 0)
#define EXP2F(x) __builtin_amdgcn_exp2f(x)

__device__ inline unsigned short f2bf(float f) {
    union { float f; unsigned u; } v; v.f = f;
    unsigned r = v.u + 0x7fffu + ((v.u >> 16) & 1u);
    return (unsigned short)(r >> 16);
}

// async global->LDS, 16B/lane; LDS dest = ldsbase + lane*16 (wave-uniform base)
__device__ inline void gload16(const unsigned short* g, unsigned short* l) {
    __builtin_amdgcn_global_load_lds(
        (const __attribute__((address_space(1))) void*)g,
        (__attribute__((address_space(3))) void*)l, 16, 0, 0);
}

// ---------------- fused fp32 -> bf16 for all 7 tensors in one dispatch --------
struct CvtP {
    const float* s[7];
    unsigned short* d[7];
};
__global__ __launch_bounds__(256) void cvt_all(CvtP p, int inpBlocks, int wBlocks) {
    int bx = blockIdx.x;
    int seg, boff;
    if (bx < 3 * inpBlocks) { seg = bx / inpBlocks; boff = bx - seg * inpBlocks; }
    else { int t = bx - 3 * inpBlocks; seg = 3 + t / wBlocks; boff = t - (seg - 3) * wBlocks; }
    int i = (boff * 256 + threadIdx.x) * 4;
    float4 f = *(const float4*)(p.s[seg] + i);
    ushort4 u;
    u.x = f2bf(f.x); u.y = f2bf(f.y); u.z = f2bf(f.z); u.w = f2bf(f.w);
    *(ushort4*)(p.d[seg] + i) = u;
}

// ---------------- fused QKV projection GEMM, m97-style 128x128 tile -----------
// out = X @ W^T + b. BM=128 BN=128 BK=32, 256 thr, 4 waves in 2x2, each 64x64.
// z=0: Qp bf16 *QSCALE; z=1: Kp bf16; z=2: V written transposed to Vt[b][h][dk][s].
__global__ __launch_bounds__(256) void gemm_qkv(
    const unsigned short* __restrict__ qb, const unsigned short* __restrict__ kb,
    const unsigned short* __restrict__ vb,
    const unsigned short* __restrict__ Wqb, const unsigned short* __restrict__ Wkb,
    const unsigned short* __restrict__ Wvb,
    const float* __restrict__ bq, const float* __restrict__ bk, const float* __restrict__ bv,
    unsigned short* __restrict__ Qp, unsigned short* __restrict__ Kp,
    unsigned short* __restrict__ Vt)
{
    __shared__ unsigned short sA[128 * 32];
    __shared__ unsigned short sB[128 * 32];

    const int z = blockIdx.z;
    const unsigned short* X = (z == 0) ? qb : (z == 1) ? kb : vb;
    const unsigned short* W = (z == 0) ? Wqb : (z == 1) ? Wkb : Wvb;
    const float* bias = (z == 0) ? bq : (z == 1) ? bk : bv;

    const int tid = threadIdx.x, lane = tid & 63, w = tid >> 6;
    const int wy = w & 1, wx = w >> 1, r = lane & 15, q = lane >> 4;
    const int m0 = blockIdx.x * 128, n0 = blockIdx.y * 128;
    const int lrow = tid >> 2, lkc = (tid & 3) * 8;

    const unsigned short* Xg = X + (size_t)(m0 + lrow) * D + lkc;
    const unsigned short* Wg = W + (size_t)(n0 + lrow) * D + lkc;

    f32x4 acc[4][4];
    #pragma unroll
    for (int mi = 0; mi < 4; ++mi)
        #pragma unroll
        for (int ni = 0; ni < 4; ++ni) acc[mi][ni] = (f32x4){0.f, 0.f, 0.f, 0.f};

    for (int k0 = 0; k0 < D; k0 += 32) {
        __syncthreads();
        gload16(Xg + k0,          sA + w * 512);
        gload16(Xg + 64 * D + k0, sA + 2048 + w * 512);
        gload16(Wg + k0,          sB + w * 512);
        gload16(Wg + 64 * D + k0, sB + 2048 + w * 512);
        __syncthreads();
        short8 af[4], bfr[4];
        #pragma unroll
        for (int mi = 0; mi < 4; ++mi)
            af[mi] = *(const short8*)(sA + (wy * 64 + mi * 16 + r) * 32 + q * 8);
        #pragma unroll
        for (int ni = 0; ni < 4; ++ni)
            bfr[ni] = *(const short8*)(sB + (wx * 64 + ni * 16 + r) * 32 + q * 8);
        #pragma unroll
        for (int mi = 0; mi < 4; ++mi)
            #pragma unroll
            for (int ni = 0; ni < 4; ++ni)
                acc[mi][ni] = MFMA16(af[mi], bfr[ni], acc[mi][ni]);
    }

    float bcol[4];
    #pragma unroll
    for (int ni = 0; ni < 4; ++ni) bcol[ni] = bias[n0 + wx * 64 + ni * 16 + r];

    #pragma unroll
    for (int mi = 0; mi < 4; ++mi)
        #pragma unroll
        for (int ni = 0; ni < 4; ++ni)
            #pragma unroll
            for (int reg = 0; reg < 4; ++reg) {
                int row = m0 + wy * 64 + mi * 16 + q * 4 + reg;
                int col = n0 + wx * 64 + ni * 16 + r;
                float val = acc[mi][ni][reg] + bcol[ni];
                if (z == 0) {
                    Qp[(size_t)row * D + col] = f2bf(val * QSCALE);
                } else if (z == 1) {
                    Kp[(size_t)row * D + col] = f2bf(val);
                } else {
                    int bb = row >> 11, s = row & (S_LEN - 1);   // S_LEN = 2048
                    int h = col >> 6, dk = col & 63;
                    Vt[(((size_t)bb * NH + h) * DK + dk) * (size_t)S_LEN + s] = f2bf(val);
                }
            }
}

// ---------------- output projection GEMM: fp32 out, 128x64 tile (2 blk/CU) ----
__global__ __launch_bounds__(256) void gemm_o(
    const unsigned short* __restrict__ X, const unsigned short* __restrict__ W,
    const float* __restrict__ bias, float* __restrict__ out)
{
    __shared__ unsigned short sA[128 * 32];
    __shared__ unsigned short sB[64 * 32];

    const int tid = threadIdx.x, lane = tid & 63, w = tid >> 6;
    const int wy = w & 1, wx = w >> 1, r = lane & 15, q = lane >> 4;
    const int m0 = blockIdx.x * 128, n0 = blockIdx.y * 64;
    const int lrow = tid >> 2, lkc = (tid & 3) * 8;

    const unsigned short* Xg = X + (size_t)(m0 + lrow) * D + lkc;
    const unsigned short* Wg = W + (size_t)(n0 + lrow) * D + lkc;

    f32x4 acc[4][2];
    #pragma unroll
    for (int mi = 0; mi < 4; ++mi)
        #pragma unroll
        for (int ni = 0; ni < 2; ++ni) acc[mi][ni] = (f32x4){0.f, 0.f, 0.f, 0.f};

    for (int k0 = 0; k0 < D; k0 += 32) {
        __syncthreads();
        gload16(Xg + k0,          sA + w * 512);
        gload16(Xg + 64 * D + k0, sA + 2048 + w * 512);
        gload16(Wg + k0,          sB + w * 512);
        __syncthreads();
        short8 af[4], bfr[2];
        #pragma unroll
        for (int mi = 0; mi < 4; ++mi)
            af[mi] = *(const short8*)(sA + (wy * 64 + mi * 16 + r) * 32 + q * 8);
        #pragma unroll
        for (int ni = 0; ni < 2; ++ni)
            bfr[ni] = *(const short8*)(sB + (wx * 32 + ni * 16 + r) * 32 + q * 8);
        #pragma unroll
        for (int mi = 0; mi < 4; ++mi)
            #pragma unroll
            for (int ni = 0; ni < 2; ++ni)
                acc[mi][ni] = MFMA16(af[mi], bfr[ni], acc[mi][ni]);
    }

    float bcol[2];
    #pragma unroll
    for (int ni = 0; ni < 2; ++ni) bcol[ni] = bias[n0 + wx * 32 + ni * 16 + r];

    #pragma unroll
    for (int mi = 0; mi < 4; ++mi)
        #pragma unroll
        for (int ni = 0; ni < 2; ++ni)
            #pragma unroll
            for (int reg = 0; reg < 4; ++reg) {
                int row = m0 + wy * 64 + mi * 16 + q * 4 + reg;
                int col = n0 + wx * 32 + ni * 16 + r;
                out[(size_t)row * D + col] = acc[mi][ni][reg] + bcol[ni];
            }
}

// ---------------- flash attention: barrier-free, operands direct from L2 ------
// Block = 128 Q rows x (head, batch); 4 waves, wave w owns rows 32w..32w+31
// (two 16-row sub-blocks rb). K and V^T fragments load straight global->VGPR
// (MFMA-ready layout; L2 serves the 4x cross-wave redundancy). P round-trips
// per-wave LDS (same-wave DS ordering, no barrier). ZERO __syncthreads:
// the compiler can overlap next-tile loads with MFMA via partial vmcnt waits.
// Q pre-scaled by 0.125*log2e -> p = exp2(score), no clamp needed.
__global__ __launch_bounds__(256, 2) void attn_bf16(
    const unsigned short* __restrict__ Qp, const unsigned short* __restrict__ Kp,
    const unsigned short* __restrict__ Vt, unsigned short* __restrict__ AO)
{
    __shared__ unsigned short sP[4][32][72];   // per-wave 32x64 (+8 pad)

    const int tid = threadIdx.x, lane = tid & 63, w = tid >> 6;
    const int r = lane & 15, q = lane >> 4;
    const int q0 = blockIdx.x * 128;
    const int h = blockIdx.y, b = blockIdx.z;
    const int S = S_LEN;

    // Q fragments: rows q0+32w+rb*16+r, two 32-wide k panels
    const unsigned short* Qbase = Qp + ((size_t)b * S + q0 + 32 * w) * D + h * DK;
    short8 qf[2][2];
    #pragma unroll
    for (int rb = 0; rb < 2; ++rb)
        #pragma unroll
        for (int c = 0; c < 2; ++c)
            qf[rb][c] = *(const short8*)(Qbase + (size_t)(rb * 16 + r) * D + c * 32 + q * 8);

    // K/V fragment bases (per-lane)
    const unsigned short* Kfb = Kp + ((size_t)b * S + r) * D + h * DK + q * 8;   // + (kv0+16j)*D + p*32
    const unsigned short* Vfb = Vt + (((size_t)b * NH + h) * DK + r) * (size_t)S + q * 8;  // + 16nb*S + kv0 + p*32

    f32x4 O[2][4];
    float psum[2][4];
    #pragma unroll
    for (int rb = 0; rb < 2; ++rb)
        #pragma unroll
        for (int i = 0; i < 4; ++i) { O[rb][i] = (f32x4){0.f, 0.f, 0.f, 0.f}; psum[rb][i] = 0.f; }

    for (int kv0 = 0; kv0 < S; kv0 += 64) {
        // ---- K fragments (B-operand: n = kv row 16j+r, k = d) ----
        short8 kf[4][2];
        #pragma unroll
        for (int j = 0; j < 4; ++j) {
            const unsigned short* Krow = Kfb + (size_t)(kv0 + 16 * j) * D;
            kf[j][0] = *(const short8*)(Krow);
            kf[j][1] = *(const short8*)(Krow + 32);
        }
        // ---- V^T fragments issued early (consumed only after softmax) ----
        short8 vf[4][2];
        #pragma unroll
        for (int nb = 0; nb < 4; ++nb) {
            const unsigned short* Vrow = Vfb + (size_t)(16 * nb) * S + kv0;
            vf[nb][0] = *(const short8*)(Vrow);
            vf[nb][1] = *(const short8*)(Vrow + 32);
        }

        // ---- scores (C-layout: qrow = q*4+reg, kv col = 16j+r) ----
        f32x4 sc[2][4];
        #pragma unroll
        for (int j = 0; j < 4; ++j)
            #pragma unroll
            for (int rb = 0; rb < 2; ++rb) {
                f32x4 t = (f32x4){0.f, 0.f, 0.f, 0.f};
                t = MFMA16(qf[rb][0], kf[j][0], t);
                t = MFMA16(qf[rb][1], kf[j][1], t);
                sc[rb][j] = t;
            }

        // ---- p = 2^score; partial row-sums; stash bf16 P ----
        #pragma unroll
        for (int rb = 0; rb < 2; ++rb)
            #pragma unroll
            for (int reg = 0; reg < 4; ++reg) {
                float p0 = EXP2F(sc[rb][0][reg]);
                float p1 = EXP2F(sc[rb][1][reg]);
                float p2 = EXP2F(sc[rb][2][reg]);
                float p3 = EXP2F(sc[rb][3][reg]);
                psum[rb][reg] += (p0 + p1) + (p2 + p3);
                int row = rb * 16 + q * 4 + reg;
                sP[w][row][r]      = f2bf(p0);
                sP[w][row][16 + r] = f2bf(p1);
                sP[w][row][32 + r] = f2bf(p2);
                sP[w][row][48 + r] = f2bf(p3);
            }

        // ---- P as A-operand (same-wave LDS roundtrip) ----
        short8 pf[2][2];
        #pragma unroll
        for (int rb = 0; rb < 2; ++rb) {
            pf[rb][0] = *(const short8*)(&sP[w][rb * 16 + r][q * 8]);
            pf[rb][1] = *(const short8*)(&sP[w][rb * 16 + r][32 + q * 8]);
        }

        // ---- O += P V ----
        #pragma unroll
        for (int nb = 0; nb < 4; ++nb)
            #pragma unroll
            for (int rb = 0; rb < 2; ++rb) {
                O[rb][nb] = MFMA16(pf[rb][0], vf[nb][0], O[rb][nb]);
                O[rb][nb] = MFMA16(pf[rb][1], vf[nb][1], O[rb][nb]);
            }
    }

    // deferred l reduction (over the 16 kv-lane groups) + normalize + store
    float inv[2][4];
    #pragma unroll
    for (int rb = 0; rb < 2; ++rb)
        #pragma unroll
        for (int reg = 0; reg < 4; ++reg) {
            float l = psum[rb][reg];
            #pragma unroll
            for (int off = 8; off > 0; off >>= 1) l += __shfl_xor(l, off);
            inv[rb][reg] = 1.0f / l;
        }

    unsigned short* Ob = AO + ((size_t)b * S + q0 + 32 * w) * D + h * DK;
    #pragma unroll
    for (int rb = 0; rb < 2; ++rb)
        #pragma unroll
        for (int reg = 0; reg < 4; ++reg)
            #pragma unroll
            for (int nb = 0; nb < 4; ++nb)
                Ob[(size_t)(rb * 16 + q * 4 + reg) * D + nb * 16 + r] =
                    f2bf(O[rb][nb][reg] * inv[rb][reg]);
}

extern "C" void kernel_launch(void* const* d_in, const int* in_sizes, int n_in,
                              void* d_out, int out_size, void* d_ws, size_t ws_size,
                              hipStream_t stream)
{
    // inputs: v, k, q, Wv, bv, Wk, bk, Wq, bq, Wo, bo  (all fp32)
    const float* v  = (const float*)d_in[0];
    const float* k  = (const float*)d_in[1];
    const float* q  = (const float*)d_in[2];
    const float* Wv = (const float*)d_in[3];
    const float* bv = (const float*)d_in[4];
    const float* Wk = (const float*)d_in[5];
    const float* bk = (const float*)d_in[6];
    const float* Wq = (const float*)d_in[7];
    const float* bq = (const float*)d_in[8];
    const float* Wo = (const float*)d_in[9];
    const float* bo = (const float*)d_in[10];
    float* out = (float*)d_out;

    const int BS = in_sizes[0] / D;   // 4096
    const int S  = S_LEN;             // 2048
    const int B  = BS / S;            // 2

    char* ws = (char*)d_ws;
    unsigned short* qb  = (unsigned short*)(ws);                 // 8.4 MB
    unsigned short* kb  = (unsigned short*)(ws + 8388608);
    unsigned short* vb  = (unsigned short*)(ws + 16777216);
    unsigned short* Wqb = (unsigned short*)(ws + 25165824);      // 2 MB each
    unsigned short* Wkb = (unsigned short*)(ws + 27262976);
    unsigned short* Wvb = (unsigned short*)(ws + 29360128);
    unsigned short* Wob = (unsigned short*)(ws + 31457280);
    unsigned short* Qp  = (unsigned short*)(ws + 33554432);
    unsigned short* Kp  = (unsigned short*)(ws + 41943040);
    unsigned short* Vt  = (unsigned short*)(ws + 50331648);
    unsigned short* AO  = qb;   // qb dead after QKV projection

    dim3 blk(256);
    const int nInp = BS * D, nW = D * D;
    const int inpBlocks = nInp / 1024, wBlocks = nW / 1024;

    CvtP cp;
    cp.s[0] = q;  cp.d[0] = qb;
    cp.s[1] = k;  cp.d[1] = kb;
    cp.s[2] = v;  cp.d[2] = vb;
    cp.s[3] = Wq; cp.d[3] = Wqb;
    cp.s[4] = Wk; cp.d[4] = Wkb;
    cp.s[5] = Wv; cp.d[5] = Wvb;
    cp.s[6] = Wo; cp.d[6] = Wob;
    cvt_all<<<3 * inpBlocks + 4 * wBlocks, blk, 0, stream>>>(cp, inpBlocks, wBlocks);

    dim3 qkvgrid(BS / 128, D / 128, 3);  // 32 x 8 x 3 = 768 blocks (3/CU)
    gemm_qkv<<<qkvgrid, blk, 0, stream>>>(qb, kb, vb, Wqb, Wkb, Wvb,
                                          bq, bk, bv, Qp, Kp, Vt);

    dim3 agrid(S / 128, NH, B);          // 16 x 16 x 2 = 512 blocks (2/CU)
    attn_bf16<<<agrid, blk, 0, stream>>>(Qp, Kp, Vt, AO);

    dim3 ogrid(BS / 128, D / 64);        // 32 x 16 = 512 blocks (2/CU)
    gemm_o<<<ogrid, blk, 0, stream>>>(AO, Wob, bo, out);
}

// Round 7
// 222.188 us; speedup vs baseline: 1.4025x; 1.4025x over previous
//
#include <hip/hip_runtime.h>
#include <math.h>

#define D 1024
#define NH 16
#define DK 64
#define S_LEN 2048
// 0.125 (1/sqrt(Dk)) * log2(e): softmax computed in base-2 domain, no max-subtraction
#define QSCALE 0.18033688011112f

using short8 = __attribute__((ext_vector_type(8))) short;   // 8 x bf16 (4 VGPR)
using f32x4  = __attribute__((ext_vector_type(4))) float;   // MFMA accumulator

#define MFMA16(a, b, c) __builtin_amdgcn_mfma_f32_16x16x32_bf16((a), (b), (c), 0, 0, 0)
#define EXP2F(x) __builtin_amdgcn_exp2f(x)

__device__ inline unsigned short f2bf(float f) {
    union { float f; unsigned u; } v; v.f = f;
    unsigned r = v.u + 0x7fffu + ((v.u >> 16) & 1u);
    return (unsigned short)(r >> 16);
}

// async global->LDS, 16B/lane; LDS dest = ldsbase + lane*16 (wave-uniform base)
__device__ inline void gload16(const unsigned short* g, unsigned short* l) {
    __builtin_amdgcn_global_load_lds(
        (const __attribute__((address_space(1))) void*)g,
        (__attribute__((address_space(3))) void*)l, 16, 0, 0);
}

// ---------------- fused fp32 -> bf16 for all 7 tensors in one dispatch --------
struct CvtP {
    const float* s[7];
    unsigned short* d[7];
};
__global__ __launch_bounds__(256) void cvt_all(CvtP p, int inpBlocks, int wBlocks) {
    int bx = blockIdx.x;
    int seg, boff;
    if (bx < 3 * inpBlocks) { seg = bx / inpBlocks; boff = bx - seg * inpBlocks; }
    else { int t = bx - 3 * inpBlocks; seg = 3 + t / wBlocks; boff = t - (seg - 3) * wBlocks; }
    int i = (boff * 256 + threadIdx.x) * 4;
    float4 f = *(const float4*)(p.s[seg] + i);
    ushort4 u;
    u.x = f2bf(f.x); u.y = f2bf(f.y); u.z = f2bf(f.z); u.w = f2bf(f.w);
    *(ushort4*)(p.d[seg] + i) = u;
}

// Fragment-swizzled layouts (per (b,h), element stride in shorts):
//  Q_sw/K_sw: [s/16 block][panel d/32][lane = (s&15) + 16*((d&31)/8)][i = d&7]
//             offset = blk16*1024 + panel*512 + lane*8 + i     (256 KB per bh)
//  V_sw:      [kv/64 tile][nb = d/16][p = (kv&63)/32][lane = (d&15) + 16*((kv&31)/8)][i = kv&7]
//             offset = kvt*4096 + nb*1024 + p*512 + lane*8 + i (256 KB per bh)
// A wave's MFMA fragment load is then one coalesced b128 at base + lane*16B.

// ---------------- fused QKV projection GEMM, 128x128 tile ---------------------
// out = X @ W^T + b. BM=128 BN=128 BK=32, 256 thr, 4 waves in 2x2, each 64x64.
// Epilogue scatters into the fragment-swizzled layouts above.
__global__ __launch_bounds__(256) void gemm_qkv(
    const unsigned short* __restrict__ qb, const unsigned short* __restrict__ kb,
    const unsigned short* __restrict__ vb,
    const unsigned short* __restrict__ Wqb, const unsigned short* __restrict__ Wkb,
    const unsigned short* __restrict__ Wvb,
    const float* __restrict__ bq, const float* __restrict__ bk, const float* __restrict__ bv,
    unsigned short* __restrict__ Qs, unsigned short* __restrict__ Ks,
    unsigned short* __restrict__ Vs)
{
    __shared__ unsigned short sA[128 * 32];
    __shared__ unsigned short sB[128 * 32];

    const int z = blockIdx.z;
    const unsigned short* X = (z == 0) ? qb : (z == 1) ? kb : vb;
    const unsigned short* W = (z == 0) ? Wqb : (z == 1) ? Wkb : Wvb;
    const float* bias = (z == 0) ? bq : (z == 1) ? bk : bv;

    const int tid = threadIdx.x, lane = tid & 63, w = tid >> 6;
    const int wy = w & 1, wx = w >> 1, r = lane & 15, q = lane >> 4;
    const int m0 = blockIdx.x * 128, n0 = blockIdx.y * 128;
    const int lrow = tid >> 2, lkc = (tid & 3) * 8;

    const unsigned short* Xg = X + (size_t)(m0 + lrow) * D + lkc;
    const unsigned short* Wg = W + (size_t)(n0 + lrow) * D + lkc;

    f32x4 acc[4][4];
    #pragma unroll
    for (int mi = 0; mi < 4; ++mi)
        #pragma unroll
        for (int ni = 0; ni < 4; ++ni) acc[mi][ni] = (f32x4){0.f, 0.f, 0.f, 0.f};

    for (int k0 = 0; k0 < D; k0 += 32) {
        __syncthreads();
        gload16(Xg + k0,          sA + w * 512);
        gload16(Xg + 64 * D + k0, sA + 2048 + w * 512);
        gload16(Wg + k0,          sB + w * 512);
        gload16(Wg + 64 * D + k0, sB + 2048 + w * 512);
        __syncthreads();
        short8 af[4], bfr[4];
        #pragma unroll
        for (int mi = 0; mi < 4; ++mi)
            af[mi] = *(const short8*)(sA + (wy * 64 + mi * 16 + r) * 32 + q * 8);
        #pragma unroll
        for (int ni = 0; ni < 4; ++ni)
            bfr[ni] = *(const short8*)(sB + (wx * 64 + ni * 16 + r) * 32 + q * 8);
        #pragma unroll
        for (int mi = 0; mi < 4; ++mi)
            #pragma unroll
            for (int ni = 0; ni < 4; ++ni)
                acc[mi][ni] = MFMA16(af[mi], bfr[ni], acc[mi][ni]);
    }

    float bcol[4];
    #pragma unroll
    for (int ni = 0; ni < 4; ++ni) bcol[ni] = bias[n0 + wx * 64 + ni * 16 + r];

    #pragma unroll
    for (int mi = 0; mi < 4; ++mi)
        #pragma unroll
        for (int ni = 0; ni < 4; ++ni)
            #pragma unroll
            for (int reg = 0; reg < 4; ++reg) {
                int row = m0 + wy * 64 + mi * 16 + q * 4 + reg;
                int col = n0 + wx * 64 + ni * 16 + r;
                float val = acc[mi][ni][reg] + bcol[ni];
                int bb = row >> 11, s = row & (S_LEN - 1);
                int hh = col >> 6, d = col & 63;
                if (z == 2) {
                    size_t off = (((size_t)bb * NH + hh) * 32 + (s >> 6)) * 4096
                               + (d >> 4) * 1024 + ((s & 63) >> 5) * 512
                               + (((s & 31) >> 3) * 16 + (d & 15)) * 8 + (s & 7);
                    Vs[off] = f2bf(val);
                } else {
                    size_t off = (((size_t)bb * NH + hh) * 128 + (s >> 4)) * 1024
                               + (d >> 5) * 512
                               + (((d & 31) >> 3) * 16 + (s & 15)) * 8 + (d & 7);
                    if (z == 0) Qs[off] = f2bf(val * QSCALE);
                    else        Ks[off] = f2bf(val);
                }
            }
}

// ---------------- output projection GEMM: fp32 out, 128x64 tile (2 blk/CU) ----
__global__ __launch_bounds__(256) void gemm_o(
    const unsigned short* __restrict__ X, const unsigned short* __restrict__ W,
    const float* __restrict__ bias, float* __restrict__ out)
{
    __shared__ unsigned short sA[128 * 32];
    __shared__ unsigned short sB[64 * 32];

    const int tid = threadIdx.x, lane = tid & 63, w = tid >> 6;
    const int wy = w & 1, wx = w >> 1, r = lane & 15, q = lane >> 4;
    const int m0 = blockIdx.x * 128, n0 = blockIdx.y * 64;
    const int lrow = tid >> 2, lkc = (tid & 3) * 8;

    const unsigned short* Xg = X + (size_t)(m0 + lrow) * D + lkc;
    const unsigned short* Wg = W + (size_t)(n0 + lrow) * D + lkc;

    f32x4 acc[4][2];
    #pragma unroll
    for (int mi = 0; mi < 4; ++mi)
        #pragma unroll
        for (int ni = 0; ni < 2; ++ni) acc[mi][ni] = (f32x4){0.f, 0.f, 0.f, 0.f};

    for (int k0 = 0; k0 < D; k0 += 32) {
        __syncthreads();
        gload16(Xg + k0,          sA + w * 512);
        gload16(Xg + 64 * D + k0, sA + 2048 + w * 512);
        gload16(Wg + k0,          sB + w * 512);
        __syncthreads();
        short8 af[4], bfr[2];
        #pragma unroll
        for (int mi = 0; mi < 4; ++mi)
            af[mi] = *(const short8*)(sA + (wy * 64 + mi * 16 + r) * 32 + q * 8);
        #pragma unroll
        for (int ni = 0; ni < 2; ++ni)
            bfr[ni] = *(const short8*)(sB + (wx * 32 + ni * 16 + r) * 32 + q * 8);
        #pragma unroll
        for (int mi = 0; mi < 4; ++mi)
            #pragma unroll
            for (int ni = 0; ni < 2; ++ni)
                acc[mi][ni] = MFMA16(af[mi], bfr[ni], acc[mi][ni]);
    }

    float bcol[2];
    #pragma unroll
    for (int ni = 0; ni < 2; ++ni) bcol[ni] = bias[n0 + wx * 32 + ni * 16 + r];

    #pragma unroll
    for (int mi = 0; mi < 4; ++mi)
        #pragma unroll
        for (int ni = 0; ni < 2; ++ni)
            #pragma unroll
            for (int reg = 0; reg < 4; ++reg) {
                int row = m0 + wy * 64 + mi * 16 + q * 4 + reg;
                int col = n0 + wx * 32 + ni * 16 + r;
                out[(size_t)row * D + col] = acc[mi][ni][reg] + bcol[ni];
            }
}

// ---------------- attention: coalesced fragment loads from L2, barrier-free ---
__device__ __attribute__((always_inline)) inline void load_kfrag(
    const unsigned short* __restrict__ Kb, int blk16, int lane, short8 (&kf)[4][2])
{
    #pragma unroll
    for (int j = 0; j < 4; ++j)
        #pragma unroll
        for (int c = 0; c < 2; ++c)
            kf[j][c] = *(const short8*)(Kb + (size_t)(blk16 + j) * 1024 + c * 512 + lane * 8);
}

__device__ __attribute__((always_inline)) inline void attn_step(
    const unsigned short* __restrict__ Vb, int kvt, int lane, int r, int q,
    const short8 (&qf)[2][2], const short8 (&kf)[4][2],
    f32x4 (&O)[2][4], float (&psum)[2][4], unsigned short* __restrict__ sPw)
{
    // V^T frags for current tile (issued early; consumed after softmax)
    short8 vf[4][2];
    #pragma unroll
    for (int nb = 0; nb < 4; ++nb)
        #pragma unroll
        for (int p = 0; p < 2; ++p)
            vf[nb][p] = *(const short8*)(Vb + (size_t)kvt * 4096 + nb * 1024 + p * 512 + lane * 8);

    // scores (C-layout: qrow = q*4+reg, kv col = 16j+r)
    f32x4 sc[2][4];
    #pragma unroll
    for (int j = 0; j < 4; ++j)
        #pragma unroll
        for (int rb = 0; rb < 2; ++rb) {
            f32x4 t = (f32x4){0.f, 0.f, 0.f, 0.f};
            t = MFMA16(qf[rb][0], kf[j][0], t);
            t = MFMA16(qf[rb][1], kf[j][1], t);
            sc[rb][j] = t;
        }

    // p = 2^score; partial row-sums; stash bf16 P (per-wave LDS, no barrier)
    #pragma unroll
    for (int rb = 0; rb < 2; ++rb)
        #pragma unroll
        for (int reg = 0; reg < 4; ++reg) {
            float p0 = EXP2F(sc[rb][0][reg]);
            float p1 = EXP2F(sc[rb][1][reg]);
            float p2 = EXP2F(sc[rb][2][reg]);
            float p3 = EXP2F(sc[rb][3][reg]);
            psum[rb][reg] += (p0 + p1) + (p2 + p3);
            int row = rb * 16 + q * 4 + reg;
            sPw[row * 72 + r]      = f2bf(p0);
            sPw[row * 72 + 16 + r] = f2bf(p1);
            sPw[row * 72 + 32 + r] = f2bf(p2);
            sPw[row * 72 + 48 + r] = f2bf(p3);
        }

    // P as A-operand (same-wave LDS roundtrip)
    short8 pf[2][2];
    #pragma unroll
    for (int rb = 0; rb < 2; ++rb) {
        pf[rb][0] = *(const short8*)(sPw + (rb * 16 + r) * 72 + q * 8);
        pf[rb][1] = *(const short8*)(sPw + (rb * 16 + r) * 72 + 32 + q * 8);
    }

    // O += P V
    #pragma unroll
    for (int nb = 0; nb < 4; ++nb)
        #pragma unroll
        for (int rb = 0; rb < 2; ++rb) {
            O[rb][nb] = MFMA16(pf[rb][0], vf[nb][0], O[rb][nb]);
            O[rb][nb] = MFMA16(pf[rb][1], vf[nb][1], O[rb][nb]);
        }
}

// Block = 128 Q rows x (head, batch); 4 waves, wave w owns rows 32w..32w+31.
// All Q/K/V fragment loads are coalesced b128 from the swizzled layouts.
// K frags double-buffered in registers (prefetch next tile during compute).
__global__ __launch_bounds__(256, 2) void attn_bf16(
    const unsigned short* __restrict__ Qs, const unsigned short* __restrict__ Ks,
    const unsigned short* __restrict__ Vs, unsigned short* __restrict__ AO)
{
    __shared__ unsigned short sP[4][32 * 72];   // per-wave 32x64 (+8 pad)

    const int tid = threadIdx.x, lane = tid & 63, w = tid >> 6;
    const int r = lane & 15, q = lane >> 4;
    const int q0 = blockIdx.x * 128;
    const int h = blockIdx.y, b = blockIdx.z;
    const int S = S_LEN;

    const unsigned short* Qb = Qs + ((size_t)b * NH + h) * 131072;
    const unsigned short* Kb = Ks + ((size_t)b * NH + h) * 131072;
    const unsigned short* Vb = Vs + ((size_t)b * NH + h) * 131072;
    unsigned short* sPw = sP[w];

    // Q fragments (coalesced, held in regs for the whole loop)
    short8 qf[2][2];
    #pragma unroll
    for (int rb = 0; rb < 2; ++rb)
        #pragma unroll
        for (int c = 0; c < 2; ++c)
            qf[rb][c] = *(const short8*)(Qb + (size_t)((q0 >> 4) + 2 * w + rb) * 1024
                                            + c * 512 + lane * 8);

    f32x4 O[2][4];
    float psum[2][4];
    #pragma unroll
    for (int rb = 0; rb < 2; ++rb)
        #pragma unroll
        for (int i = 0; i < 4; ++i) { O[rb][i] = (f32x4){0.f, 0.f, 0.f, 0.f}; psum[rb][i] = 0.f; }

    short8 kfA[4][2], kfB[4][2];
    load_kfrag(Kb, 0, lane, kfA);

    for (int kvt = 0; kvt < 32; kvt += 2) {
        int n1 = (kvt + 1 < 32) ? (kvt + 1) * 4 : 124;
        load_kfrag(Kb, n1, lane, kfB);
        attn_step(Vb, kvt, lane, r, q, qf, kfA, O, psum, sPw);
        int n2 = (kvt + 2 < 32) ? (kvt + 2) * 4 : 124;
        load_kfrag(Kb, n2, lane, kfA);
        attn_step(Vb, kvt + 1, lane, r, q, qf, kfB, O, psum, sPw);
    }

    // deferred l reduction (over the 16 kv-lane groups) + normalize + store
    float inv[2][4];
    #pragma unroll
    for (int rb = 0; rb < 2; ++rb)
        #pragma unroll
        for (int reg = 0; reg < 4; ++reg) {
            float l = psum[rb][reg];
            #pragma unroll
            for (int off = 8; off > 0; off >>= 1) l += __shfl_xor(l, off);
            inv[rb][reg] = 1.0f / l;
        }

    unsigned short* Ob = AO + ((size_t)b * S + q0 + 32 * w) * D + h * DK;
    #pragma unroll
    for (int rb = 0; rb < 2; ++rb)
        #pragma unroll
        for (int reg = 0; reg < 4; ++reg)
            #pragma unroll
            for (int nb = 0; nb < 4; ++nb)
                Ob[(size_t)(rb * 16 + q * 4 + reg) * D + nb * 16 + r] =
                    f2bf(O[rb][nb][reg] * inv[rb][reg]);
}

extern "C" void kernel_launch(void* const* d_in, const int* in_sizes, int n_in,
                              void* d_out, int out_size, void* d_ws, size_t ws_size,
                              hipStream_t stream)
{
    // inputs: v, k, q, Wv, bv, Wk, bk, Wq, bq, Wo, bo  (all fp32)
    const float* v  = (const float*)d_in[0];
    const float* k  = (const float*)d_in[1];
    const float* q  = (const float*)d_in[2];
    const float* Wv = (const float*)d_in[3];
    const float* bv = (const float*)d_in[4];
    const float* Wk = (const float*)d_in[5];
    const float* bk = (const float*)d_in[6];
    const float* Wq = (const float*)d_in[7];
    const float* bq = (const float*)d_in[8];
    const float* Wo = (const float*)d_in[9];
    const float* bo = (const float*)d_in[10];
    float* out = (float*)d_out;

    const int BS = in_sizes[0] / D;   // 4096
    const int S  = S_LEN;             // 2048
    const int B  = BS / S;            // 2

    char* ws = (char*)d_ws;
    unsigned short* qb  = (unsigned short*)(ws);                 // 8.4 MB
    unsigned short* kb  = (unsigned short*)(ws + 8388608);
    unsigned short* vb  = (unsigned short*)(ws + 16777216);
    unsigned short* Wqb = (unsigned short*)(ws + 25165824);      // 2 MB each
    unsigned short* Wkb = (unsigned short*)(ws + 27262976);
    unsigned short* Wvb = (unsigned short*)(ws + 29360128);
    unsigned short* Wob = (unsigned short*)(ws + 31457280);
    unsigned short* Qs  = (unsigned short*)(ws + 33554432);
    unsigned short* Ks  = (unsigned short*)(ws + 41943040);
    unsigned short* Vs  = (unsigned short*)(ws + 50331648);
    unsigned short* AO  = qb;   // qb dead after QKV projection

    dim3 blk(256);
    const int nInp = BS * D, nW = D * D;
    const int inpBlocks = nInp / 1024, wBlocks = nW / 1024;

    CvtP cp;
    cp.s[0] = q;  cp.d[0] = qb;
    cp.s[1] = k;  cp.d[1] = kb;
    cp.s[2] = v;  cp.d[2] = vb;
    cp.s[3] = Wq; cp.d[3] = Wqb;
    cp.s[4] = Wk; cp.d[4] = Wkb;
    cp.s[5] = Wv; cp.d[5] = Wvb;
    cp.s[6] = Wo; cp.d[6] = Wob;
    cvt_all<<<3 * inpBlocks + 4 * wBlocks, blk, 0, stream>>>(cp, inpBlocks, wBlocks);

    dim3 qkvgrid(BS / 128, D / 128, 3);  // 32 x 8 x 3 = 768 blocks (3/CU)
    gemm_qkv<<<qkvgrid, blk, 0, stream>>>(qb, kb, vb, Wqb, Wkb, Wvb,
                                          bq, bk, bv, Qs, Ks, Vs);

    dim3 agrid(S / 128, NH, B);          // 16 x 16 x 2 = 512 blocks (2/CU)
    attn_bf16<<<agrid, blk, 0, stream>>>(Qs, Ks, Vs, AO);

    dim3 ogrid(BS / 128, D / 64);        // 32 x 16 = 512 blocks (2/CU)
    gemm_o<<<ogrid, blk, 0, stream>>>(AO, Wob, bo, out);
}